// Round 2
// baseline (2006.022 us; speedup 1.0000x reference)
//
#include <hip/hip_runtime.h>
#include <hip/hip_bf16.h>

// LSTMEncoder: B=65536, T=25, I=4, H=64, 2 layers, out = h2 at t=4,9,14,19,24.
// Split-precision matmul (v = hi + lo bf16 pairs) for f32-accurate trajectory:
//   h@W ~= h_hi@W_hi + h_hi@W_lo + h_lo@W_hi  (exact products, f32 MFMA acc)
// Elementwise pure f32 (hw exp2/rcp).
//
// R7: wave specialization (waves 0-3 = layer 1, 4-7 = layer 2), 1 barrier/iter.
// R8: pre-split weights into d_ws (killed per-iter splitf remat; -16us only).
// R9 (this round): 2 BLOCKS/CU. R8 counters: VGPR=128, LDS=83,968B -> LDS caps
// residency at 1 block/CU (2 waves/SIMD, Occupancy 23%); 13,300 cyc/iter vs
// ~3-4k cycles of issue work = latency-bound (serial MFMA accumulator chains +
// serial elementwise chains, nothing to hide them with). XB stride 40->24
// shorts (only k=0..11 of the x fragment is live; k>=12 multiplies zero B rows;
// +8-short pad keeps last-row overread in-bounds) cuts LDS to 79,904B <=
// 81,920B -> 2 blocks/CU. __launch_bounds__(512,4) pins the already-natural
// 128 VGPRs so 4 waves/SIMD actually materializes.
//
// MFMA 16x16x32 bf16 layouts (measured, learn_hip m89/m120):
//   A[m][k]: m=lane&15, k=(lane>>4)*8+e ; B[k][n]: n=lane&15, k=(lane>>4)*8+e
//   C/D    : col=lane&15, row=(lane>>4)*4+reg

typedef short short8 __attribute__((ext_vector_type(8)));
typedef float floatx4 __attribute__((ext_vector_type(4)));

namespace {
constexpr int T_ = 25;
constexpr int I_ = 4;
constexpr int MB = 64;     // batch rows per block
constexpr int HSTR = 72;   // LDS row stride (shorts): 144B, 16B-aligned, 2-way banks
constexpr int XSTR = 24;   // x tile stride (shorts): 48B, 2-way banks
constexpr int XPAD = 8;    // last-row overread pad (q=3 reads offs 24..31)

// Workspace layout, in short8 (16B fragment-row) units:
//   BX  : [g][w][lane]        -> 4*4*64   = 1024 rows (Wih0, k-packed hi/lo)
//   HH0 : [g][hf][w][lane]    -> 4*2*4*64 = 2048 rows each for hi and lo
//   IH1 : same shape          -> 2048 rows each
//   HH1 : same shape          -> 2048 rows each
constexpr int OFF_BX   = 0;
constexpr int OFF_HH0H = 1024;
constexpr int OFF_HH0L = 3072;
constexpr int OFF_IH1H = 5120;
constexpr int OFF_IH1L = 7168;
constexpr int OFF_HH1H = 9216;
constexpr int OFF_HH1L = 11264;
}

__device__ __forceinline__ float sigm_(float x) {
  float t = __builtin_amdgcn_exp2f(x * -1.44269504088896340736f);  // e^-x
  return __builtin_amdgcn_rcpf(1.0f + t);
}
__device__ __forceinline__ float tanh_(float x) {
  float t = __builtin_amdgcn_exp2f(x * -2.88539008177792681472f);  // e^-2x
  return 2.0f * __builtin_amdgcn_rcpf(1.0f + t) - 1.0f;
}
__device__ __forceinline__ unsigned short f2bf_(float f) {  // RNE f32->bf16
  unsigned u = __float_as_uint(f);
  u += 0x7FFFu + ((u >> 16) & 1u);
  return (unsigned short)(u >> 16);
}
__device__ __forceinline__ float bf2f_(unsigned short s) {
  return __uint_as_float(((unsigned)s) << 16);
}
__device__ __forceinline__ void splitf_(float f, unsigned short& hi, unsigned short& lo) {
  hi = f2bf_(f);
  lo = f2bf_(f - bf2f_(hi));
}

// ---------------------------------------------------------------------------
// Prep kernel: split weights once into fragment-ordered hi/lo short8 rows.
// One thread per fragment row (7168 total). Bit-identical to in-kernel split.
// ---------------------------------------------------------------------------
__global__ void prep_weights(const float* __restrict__ Wih0,   // [256,4]
                             const float* __restrict__ Whh0,   // [256,64]
                             const float* __restrict__ Wih1,   // [256,64]
                             const float* __restrict__ Whh1,   // [256,64]
                             unsigned short* __restrict__ ws) {
  const int t = blockIdx.x * 256 + threadIdx.x;
  if (t < 1024) {
    // BX rows: t = g*256 + w*64 + lane. K-packed Wih0 fragment:
    //   q==0: e0..3 = hi(W[n][e]), e4..7 = lo(W[n][e-4])
    //   q==1: e0..3 = hi(W[n][e]) (pairs x_lo at k=8..11); rest 0
    const int lane = t & 63, w = (t >> 6) & 3, g = t >> 8;
    const int l = lane & 15, q = lane >> 4;
    const int n = g * 64 + w * 16 + l;
    unsigned short row[8];
#pragma unroll
    for (int e = 0; e < 8; ++e) row[e] = 0;
    if (q < 2) {
#pragma unroll
      for (int e = 0; e < 4; ++e) {
        unsigned short h, lo;
        splitf_(Wih0[n * 4 + e], h, lo);
        row[e] = h;
        if (q == 0) row[4 + e] = lo;
      }
    }
#pragma unroll
    for (int e = 0; e < 8; ++e) ws[(OFF_BX + t) * 8 + e] = row[e];
  } else if (t < 7168) {
    const int a = (t - 1024) >> 11;    // 0:Whh0 1:Wih1 2:Whh1
    const int r = (t - 1024) & 2047;   // r = g*512 + hf*256 + w*64 + lane
    const int lane = r & 63, w = (r >> 6) & 3, hf = (r >> 8) & 1, g = r >> 9;
    const int l = lane & 15, q = lane >> 4;
    const int n = g * 64 + w * 16 + l;
    const float* src = (a == 0) ? Whh0 : (a == 1) ? Wih1 : Whh1;
    const int offH = (a == 0) ? OFF_HH0H : (a == 1) ? OFF_IH1H : OFF_HH1H;
    const int offL = offH + 2048;
#pragma unroll
    for (int e = 0; e < 8; ++e) {
      unsigned short h, lo;
      splitf_(src[n * 64 + hf * 32 + q * 8 + e], h, lo);
      ws[(offH + r) * 8 + e] = h;
      ws[(offL + r) * 8 + e] = lo;
    }
  }
}

// ---------------------------------------------------------------------------
// Main kernel
// ---------------------------------------------------------------------------
__global__ __launch_bounds__(512, 4)
void lstm2_kernel(const float* __restrict__ x,     // [B,25,4]
                  const float* __restrict__ b0,    // [256]
                  const float* __restrict__ b1,    // [256]
                  const short8* __restrict__ wf,   // pre-split weight frags
                  float* __restrict__ out) {       // [B,5,64]
  // h1(t) lives in H1*[t&1]; h2(t) in H2*[t&1]; x(t) in XB[t&1].
  __shared__ __align__(16) unsigned short H1h[2][MB * HSTR];
  __shared__ __align__(16) unsigned short H1l[2][MB * HSTR];
  __shared__ __align__(16) unsigned short H2h[2][MB * HSTR];
  __shared__ __align__(16) unsigned short H2l[2][MB * HSTR];
  __shared__ __align__(16) unsigned short XB[2][MB * XSTR + XPAD];

  const int tid = threadIdx.x;
  const int lane = tid & 63;
  const int w = tid >> 6;   // 0..7
  const int l = lane & 15;
  const int q = lane >> 4;
  const int mbase = blockIdx.x * MB;

  // ---- init LDS: zero the [1] state buffers (h(-1)=0) + both XB buffers ----
  for (int idx = tid; idx < MB * 64; idx += 512) {
    int m = idx >> 6, k = idx & 63;
    H1h[1][m * HSTR + k] = 0;
    H1l[1][m * HSTR + k] = 0;
    H2h[1][m * HSTR + k] = 0;
    H2l[1][m * HSTR + k] = 0;
  }
  for (int idx = tid; idx < 2 * (MB * XSTR + XPAD); idx += 512) (&XB[0][0])[idx] = 0;
  if (tid < 256) {  // stage x(0) into XB[0]
    int m = tid >> 2, ii = tid & 3;
    unsigned short xh, xl;
    splitf_(x[(mbase + m) * (T_ * I_) + ii], xh, xl);
    XB[0][m * XSTR + ii] = xh;
    XB[0][m * XSTR + 4 + ii] = xh;
    XB[0][m * XSTR + 8 + ii] = xl;
  }
  __syncthreads();

  if (w < 4) {
    // ==================== LAYER-1 WAVES (0..3) ====================
    const int j = w * 16 + l;  // hidden col owned (all 4 gates)
    short8 B1h[4][2], B1l[4][2], BXf[4];
    floatx4 bias0v[4];
#pragma unroll
    for (int g = 0; g < 4; ++g) {
      BXf[g] = wf[OFF_BX + g * 256 + w * 64 + lane];
#pragma unroll
      for (int hf = 0; hf < 2; ++hf) {
        B1h[g][hf] = wf[OFF_HH0H + (g * 2 + hf) * 256 + w * 64 + lane];
        B1l[g][hf] = wf[OFF_HH0L + (g * 2 + hf) * 256 + w * 64 + lane];
      }
      float bb = b0[g * 64 + j];
      bias0v[g] = (floatx4){bb, bb, bb, bb};
    }
    float c1[16];
#pragma unroll
    for (int k = 0; k < 16; ++k) c1[k] = 0.f;

#pragma unroll 1
    for (int tt = 0; tt < T_ + 1; ++tt) {
      if (tt < T_) {
        const int p = tt & 1;  // write h1(tt) -> H1*[p]; read h1(tt-1) <- H1*[p^1]
#pragma unroll
        for (int mt = 0; mt < 4; ++mt) {
          const int row = mt * 16 + l;
          short8 a0h = *(const short8*)&H1h[p ^ 1][row * HSTR + q * 8];
          short8 a1h = *(const short8*)&H1h[p ^ 1][row * HSTR + 32 + q * 8];
          short8 a0l = *(const short8*)&H1l[p ^ 1][row * HSTR + q * 8];
          short8 a1l = *(const short8*)&H1l[p ^ 1][row * HSTR + 32 + q * 8];
          short8 ax  = *(const short8*)&XB[p][row * XSTR + q * 8];
          floatx4 zs[4];
#pragma unroll
          for (int g = 0; g < 4; ++g) {
            floatx4 a_ = bias0v[g];
            a_ = __builtin_amdgcn_mfma_f32_16x16x32_bf16(ax,  BXf[g],    a_, 0, 0, 0);
            a_ = __builtin_amdgcn_mfma_f32_16x16x32_bf16(a0h, B1h[g][0], a_, 0, 0, 0);
            a_ = __builtin_amdgcn_mfma_f32_16x16x32_bf16(a1h, B1h[g][1], a_, 0, 0, 0);
            a_ = __builtin_amdgcn_mfma_f32_16x16x32_bf16(a0h, B1l[g][0], a_, 0, 0, 0);
            a_ = __builtin_amdgcn_mfma_f32_16x16x32_bf16(a1h, B1l[g][1], a_, 0, 0, 0);
            a_ = __builtin_amdgcn_mfma_f32_16x16x32_bf16(a0l, B1h[g][0], a_, 0, 0, 0);
            a_ = __builtin_amdgcn_mfma_f32_16x16x32_bf16(a1l, B1h[g][1], a_, 0, 0, 0);
            zs[g] = a_;
          }
#pragma unroll
          for (int r = 0; r < 4; ++r) {
            float si = sigm_(zs[0][r]);
            float sf = sigm_(zs[1][r]);
            float tg = tanh_(zs[2][r]);
            float so = sigm_(zs[3][r]);
            float cc = sf * c1[mt * 4 + r] + si * tg;
            c1[mt * 4 + r] = cc;
            float h = so * tanh_(cc);
            unsigned short hh, hl;
            splitf_(h, hh, hl);
            const int m = mt * 16 + q * 4 + r;
            H1h[p][m * HSTR + j] = hh;
            H1l[p][m * HSTR + j] = hl;
          }
        }
        if (tt + 1 < T_) {  // stage x(tt+1) into the other XB buffer
          int m = (tid & 255) >> 2, ii = tid & 3;
          unsigned short xh, xl;
          splitf_(x[(mbase + m) * (T_ * I_) + (tt + 1) * I_ + ii], xh, xl);
          XB[(tt + 1) & 1][m * XSTR + ii] = xh;
          XB[(tt + 1) & 1][m * XSTR + 4 + ii] = xh;
          XB[(tt + 1) & 1][m * XSTR + 8 + ii] = xl;
        }
      }
      __syncthreads();  // barrier 1-per-iter, matched with L2 branch
    }
  } else {
    // ==================== LAYER-2 WAVES (4..7) ====================
    const int w2 = w - 4;
    const int j = w2 * 16 + l;
    short8 B2h[4][4], B2l[4][4];  // [0..1]=Wih1, [2..3]=Whh1
    floatx4 bias1v[4];
#pragma unroll
    for (int g = 0; g < 4; ++g) {
#pragma unroll
      for (int hf = 0; hf < 2; ++hf) {
        B2h[g][hf]     = wf[OFF_IH1H + (g * 2 + hf) * 256 + w2 * 64 + lane];
        B2l[g][hf]     = wf[OFF_IH1L + (g * 2 + hf) * 256 + w2 * 64 + lane];
        B2h[g][2 + hf] = wf[OFF_HH1H + (g * 2 + hf) * 256 + w2 * 64 + lane];
        B2l[g][2 + hf] = wf[OFF_HH1L + (g * 2 + hf) * 256 + w2 * 64 + lane];
      }
      float bb = b1[g * 64 + j];
      bias1v[g] = (floatx4){bb, bb, bb, bb};
    }
    float c2[16];
#pragma unroll
    for (int k = 0; k < 16; ++k) c2[k] = 0.f;

#pragma unroll 1
    for (int tt = 0; tt < T_ + 1; ++tt) {
      if (tt >= 1) {
        const int t2 = tt - 1;   // computing h2(t2)
        const int p2 = t2 & 1;   // read h1(t2) <- H1*[p2], h2(t2-1) <- H2*[p2^1]
        const bool do_out = (t2 % 5 == 4);
        const int kk = t2 / 5;
#pragma unroll
        for (int mt = 0; mt < 4; ++mt) {
          const int row = mt * 16 + l;
          short8 n0h = *(const short8*)&H1h[p2][row * HSTR + q * 8];
          short8 n1h = *(const short8*)&H1h[p2][row * HSTR + 32 + q * 8];
          short8 n0l = *(const short8*)&H1l[p2][row * HSTR + q * 8];
          short8 n1l = *(const short8*)&H1l[p2][row * HSTR + 32 + q * 8];
          short8 m0h = *(const short8*)&H2h[p2 ^ 1][row * HSTR + q * 8];
          short8 m1h = *(const short8*)&H2h[p2 ^ 1][row * HSTR + 32 + q * 8];
          short8 m0l = *(const short8*)&H2l[p2 ^ 1][row * HSTR + q * 8];
          short8 m1l = *(const short8*)&H2l[p2 ^ 1][row * HSTR + 32 + q * 8];
          floatx4 zs[4];
#pragma unroll
          for (int g = 0; g < 4; ++g) {
            floatx4 a_ = bias1v[g];
            a_ = __builtin_amdgcn_mfma_f32_16x16x32_bf16(n0h, B2h[g][0], a_, 0, 0, 0);
            a_ = __builtin_amdgcn_mfma_f32_16x16x32_bf16(n1h, B2h[g][1], a_, 0, 0, 0);
            a_ = __builtin_amdgcn_mfma_f32_16x16x32_bf16(n0h, B2l[g][0], a_, 0, 0, 0);
            a_ = __builtin_amdgcn_mfma_f32_16x16x32_bf16(n1h, B2l[g][1], a_, 0, 0, 0);
            a_ = __builtin_amdgcn_mfma_f32_16x16x32_bf16(n0l, B2h[g][0], a_, 0, 0, 0);
            a_ = __builtin_amdgcn_mfma_f32_16x16x32_bf16(n1l, B2h[g][1], a_, 0, 0, 0);
            a_ = __builtin_amdgcn_mfma_f32_16x16x32_bf16(m0h, B2h[g][2], a_, 0, 0, 0);
            a_ = __builtin_amdgcn_mfma_f32_16x16x32_bf16(m1h, B2h[g][3], a_, 0, 0, 0);
            a_ = __builtin_amdgcn_mfma_f32_16x16x32_bf16(m0h, B2l[g][2], a_, 0, 0, 0);
            a_ = __builtin_amdgcn_mfma_f32_16x16x32_bf16(m1h, B2l[g][3], a_, 0, 0, 0);
            a_ = __builtin_amdgcn_mfma_f32_16x16x32_bf16(m0l, B2h[g][2], a_, 0, 0, 0);
            a_ = __builtin_amdgcn_mfma_f32_16x16x32_bf16(m1l, B2h[g][3], a_, 0, 0, 0);
            zs[g] = a_;
          }
#pragma unroll
          for (int r = 0; r < 4; ++r) {
            float si = sigm_(zs[0][r]);
            float sf = sigm_(zs[1][r]);
            float tg = tanh_(zs[2][r]);
            float so = sigm_(zs[3][r]);
            float cc = sf * c2[mt * 4 + r] + si * tg;
            c2[mt * 4 + r] = cc;
            float h = so * tanh_(cc);
            unsigned short hh, hl;
            splitf_(h, hh, hl);
            const int m = mt * 16 + q * 4 + r;
            H2h[p2][m * HSTR + j] = hh;
            H2l[p2][m * HSTR + j] = hl;
            if (do_out) out[(size_t)(mbase + m) * 320 + (size_t)kk * 64 + j] = h;
          }
        }
      }
      __syncthreads();  // matched with L1 branch
    }
  }
}

extern "C" void kernel_launch(void* const* d_in, const int* in_sizes, int n_in,
                              void* d_out, int out_size, void* d_ws, size_t ws_size,
                              hipStream_t stream) {
  const float* xp   = (const float*)d_in[0];
  const float* Wih0 = (const float*)d_in[1];
  const float* Whh0 = (const float*)d_in[2];
  const float* b0   = (const float*)d_in[3];
  const float* Wih1 = (const float*)d_in[4];
  const float* Whh1 = (const float*)d_in[5];
  const float* b1   = (const float*)d_in[6];
  float* outp = (float*)d_out;
  unsigned short* ws = (unsigned short*)d_ws;

  // Pre-split weights into fragment-ordered hi/lo arrays (212992 B of d_ws).
  hipLaunchKernelGGL(prep_weights, dim3(28), dim3(256), 0, stream,
                     Wih0, Whh0, Wih1, Whh1, ws);

  const int B = in_sizes[0] / (T_ * I_);  // 65536
  dim3 grid(B / MB), block(512);
  hipLaunchKernelGGL(lstm2_kernel, grid, block, 0, stream,
                     xp, b0, b1, (const short8*)ws, outp);
}

// Round 3
// 581.439 us; speedup vs baseline: 3.4501x; 3.4501x over previous
//
#include <hip/hip_runtime.h>
#include <hip/hip_bf16.h>

// LSTMEncoder: B=65536, T=25, I=4, H=64, 2 layers, out = h2 at t=4,9,14,19,24.
// Split-precision matmul (v = hi + lo bf16 pairs) for f32-accurate trajectory:
//   h@W ~= h_hi@W_hi + h_hi@W_lo + h_lo@W_hi  (exact products, f32 MFMA acc)
// Elementwise pure f32 (hw exp2/rcp).
//
// R7: wave specialization (waves 0-3 = layer 1, 4-7 = layer 2), 1 barrier/iter.
// R8: pre-split weights into d_ws (killed per-iter splitf remat).
// R9: XSTR 40->24 shrank LDS to 80,384B -> 2 blocks/CU PROVEN (Occupancy 47.6)
//     but __launch_bounds__(512,4) clamped VGPR to 64 -> total spill to scratch
//     (FETCH 5.4GB, 3.3TB/s scratch traffic, 2006us). Empirical on this
//     toolchain: arg=2 => 128-reg cap (R8 measured), arg=4 => 64-reg cap.
// R10 (this round): keep XSTR=24 LDS squeeze, revert to __launch_bounds__(512,2)
//     -> 128 VGPR (exactly the 4-waves/SIMD budget, R8-proven no-spill) x
//     2 resident blocks/CU. Two phase-offset blocks per CU overlap each
//     other's MFMA-chain + elementwise latency and barrier drains.
//
// MFMA 16x16x32 bf16 layouts (measured, learn_hip m89/m120):
//   A[m][k]: m=lane&15, k=(lane>>4)*8+e ; B[k][n]: n=lane&15, k=(lane>>4)*8+e
//   C/D    : col=lane&15, row=(lane>>4)*4+reg

typedef short short8 __attribute__((ext_vector_type(8)));
typedef float floatx4 __attribute__((ext_vector_type(4)));

namespace {
constexpr int T_ = 25;
constexpr int I_ = 4;
constexpr int MB = 64;     // batch rows per block
constexpr int HSTR = 72;   // LDS row stride (shorts): 144B, 16B-aligned, 2-way banks
constexpr int XSTR = 24;   // x tile stride (shorts): 48B, 2-way banks
constexpr int XPAD = 8;    // last-row overread pad (q=3 reads offs 24..31)

// Workspace layout, in short8 (16B fragment-row) units:
//   BX  : [g][w][lane]        -> 4*4*64   = 1024 rows (Wih0, k-packed hi/lo)
//   HH0 : [g][hf][w][lane]    -> 4*2*4*64 = 2048 rows each for hi and lo
//   IH1 : same shape          -> 2048 rows each
//   HH1 : same shape          -> 2048 rows each
constexpr int OFF_BX   = 0;
constexpr int OFF_HH0H = 1024;
constexpr int OFF_HH0L = 3072;
constexpr int OFF_IH1H = 5120;
constexpr int OFF_IH1L = 7168;
constexpr int OFF_HH1H = 9216;
constexpr int OFF_HH1L = 11264;
}

__device__ __forceinline__ float sigm_(float x) {
  float t = __builtin_amdgcn_exp2f(x * -1.44269504088896340736f);  // e^-x
  return __builtin_amdgcn_rcpf(1.0f + t);
}
__device__ __forceinline__ float tanh_(float x) {
  float t = __builtin_amdgcn_exp2f(x * -2.88539008177792681472f);  // e^-2x
  return 2.0f * __builtin_amdgcn_rcpf(1.0f + t) - 1.0f;
}
__device__ __forceinline__ unsigned short f2bf_(float f) {  // RNE f32->bf16
  unsigned u = __float_as_uint(f);
  u += 0x7FFFu + ((u >> 16) & 1u);
  return (unsigned short)(u >> 16);
}
__device__ __forceinline__ float bf2f_(unsigned short s) {
  return __uint_as_float(((unsigned)s) << 16);
}
__device__ __forceinline__ void splitf_(float f, unsigned short& hi, unsigned short& lo) {
  hi = f2bf_(f);
  lo = f2bf_(f - bf2f_(hi));
}

// ---------------------------------------------------------------------------
// Prep kernel: split weights once into fragment-ordered hi/lo short8 rows.
// One thread per fragment row (7168 total). Bit-identical to in-kernel split.
// ---------------------------------------------------------------------------
__global__ void prep_weights(const float* __restrict__ Wih0,   // [256,4]
                             const float* __restrict__ Whh0,   // [256,64]
                             const float* __restrict__ Wih1,   // [256,64]
                             const float* __restrict__ Whh1,   // [256,64]
                             unsigned short* __restrict__ ws) {
  const int t = blockIdx.x * 256 + threadIdx.x;
  if (t < 1024) {
    // BX rows: t = g*256 + w*64 + lane. K-packed Wih0 fragment:
    //   q==0: e0..3 = hi(W[n][e]), e4..7 = lo(W[n][e-4])
    //   q==1: e0..3 = hi(W[n][e]) (pairs x_lo at k=8..11); rest 0
    const int lane = t & 63, w = (t >> 6) & 3, g = t >> 8;
    const int l = lane & 15, q = lane >> 4;
    const int n = g * 64 + w * 16 + l;
    unsigned short row[8];
#pragma unroll
    for (int e = 0; e < 8; ++e) row[e] = 0;
    if (q < 2) {
#pragma unroll
      for (int e = 0; e < 4; ++e) {
        unsigned short h, lo;
        splitf_(Wih0[n * 4 + e], h, lo);
        row[e] = h;
        if (q == 0) row[4 + e] = lo;
      }
    }
#pragma unroll
    for (int e = 0; e < 8; ++e) ws[(OFF_BX + t) * 8 + e] = row[e];
  } else if (t < 7168) {
    const int a = (t - 1024) >> 11;    // 0:Whh0 1:Wih1 2:Whh1
    const int r = (t - 1024) & 2047;   // r = g*512 + hf*256 + w*64 + lane
    const int lane = r & 63, w = (r >> 6) & 3, hf = (r >> 8) & 1, g = r >> 9;
    const int l = lane & 15, q = lane >> 4;
    const int n = g * 64 + w * 16 + l;
    const float* src = (a == 0) ? Whh0 : (a == 1) ? Wih1 : Whh1;
    const int offH = (a == 0) ? OFF_HH0H : (a == 1) ? OFF_IH1H : OFF_HH1H;
    const int offL = offH + 2048;
#pragma unroll
    for (int e = 0; e < 8; ++e) {
      unsigned short h, lo;
      splitf_(src[n * 64 + hf * 32 + q * 8 + e], h, lo);
      ws[(offH + r) * 8 + e] = h;
      ws[(offL + r) * 8 + e] = lo;
    }
  }
}

// ---------------------------------------------------------------------------
// Main kernel
// ---------------------------------------------------------------------------
__global__ __launch_bounds__(512, 2)
void lstm2_kernel(const float* __restrict__ x,     // [B,25,4]
                  const float* __restrict__ b0,    // [256]
                  const float* __restrict__ b1,    // [256]
                  const short8* __restrict__ wf,   // pre-split weight frags
                  float* __restrict__ out) {       // [B,5,64]
  // h1(t) lives in H1*[t&1]; h2(t) in H2*[t&1]; x(t) in XB[t&1].
  __shared__ __align__(16) unsigned short H1h[2][MB * HSTR];
  __shared__ __align__(16) unsigned short H1l[2][MB * HSTR];
  __shared__ __align__(16) unsigned short H2h[2][MB * HSTR];
  __shared__ __align__(16) unsigned short H2l[2][MB * HSTR];
  __shared__ __align__(16) unsigned short XB[2][MB * XSTR + XPAD];

  const int tid = threadIdx.x;
  const int lane = tid & 63;
  const int w = tid >> 6;   // 0..7
  const int l = lane & 15;
  const int q = lane >> 4;
  const int mbase = blockIdx.x * MB;

  // ---- init LDS: zero the [1] state buffers (h(-1)=0) + both XB buffers ----
  for (int idx = tid; idx < MB * 64; idx += 512) {
    int m = idx >> 6, k = idx & 63;
    H1h[1][m * HSTR + k] = 0;
    H1l[1][m * HSTR + k] = 0;
    H2h[1][m * HSTR + k] = 0;
    H2l[1][m * HSTR + k] = 0;
  }
  for (int idx = tid; idx < 2 * (MB * XSTR + XPAD); idx += 512) (&XB[0][0])[idx] = 0;
  if (tid < 256) {  // stage x(0) into XB[0]
    int m = tid >> 2, ii = tid & 3;
    unsigned short xh, xl;
    splitf_(x[(mbase + m) * (T_ * I_) + ii], xh, xl);
    XB[0][m * XSTR + ii] = xh;
    XB[0][m * XSTR + 4 + ii] = xh;
    XB[0][m * XSTR + 8 + ii] = xl;
  }
  __syncthreads();

  if (w < 4) {
    // ==================== LAYER-1 WAVES (0..3) ====================
    const int j = w * 16 + l;  // hidden col owned (all 4 gates)
    short8 B1h[4][2], B1l[4][2], BXf[4];
    floatx4 bias0v[4];
#pragma unroll
    for (int g = 0; g < 4; ++g) {
      BXf[g] = wf[OFF_BX + g * 256 + w * 64 + lane];
#pragma unroll
      for (int hf = 0; hf < 2; ++hf) {
        B1h[g][hf] = wf[OFF_HH0H + (g * 2 + hf) * 256 + w * 64 + lane];
        B1l[g][hf] = wf[OFF_HH0L + (g * 2 + hf) * 256 + w * 64 + lane];
      }
      float bb = b0[g * 64 + j];
      bias0v[g] = (floatx4){bb, bb, bb, bb};
    }
    float c1[16];
#pragma unroll
    for (int k = 0; k < 16; ++k) c1[k] = 0.f;

#pragma unroll 1
    for (int tt = 0; tt < T_ + 1; ++tt) {
      if (tt < T_) {
        const int p = tt & 1;  // write h1(tt) -> H1*[p]; read h1(tt-1) <- H1*[p^1]
#pragma unroll
        for (int mt = 0; mt < 4; ++mt) {
          const int row = mt * 16 + l;
          short8 a0h = *(const short8*)&H1h[p ^ 1][row * HSTR + q * 8];
          short8 a1h = *(const short8*)&H1h[p ^ 1][row * HSTR + 32 + q * 8];
          short8 a0l = *(const short8*)&H1l[p ^ 1][row * HSTR + q * 8];
          short8 a1l = *(const short8*)&H1l[p ^ 1][row * HSTR + 32 + q * 8];
          short8 ax  = *(const short8*)&XB[p][row * XSTR + q * 8];
          floatx4 zs[4];
#pragma unroll
          for (int g = 0; g < 4; ++g) {
            floatx4 a_ = bias0v[g];
            a_ = __builtin_amdgcn_mfma_f32_16x16x32_bf16(ax,  BXf[g],    a_, 0, 0, 0);
            a_ = __builtin_amdgcn_mfma_f32_16x16x32_bf16(a0h, B1h[g][0], a_, 0, 0, 0);
            a_ = __builtin_amdgcn_mfma_f32_16x16x32_bf16(a1h, B1h[g][1], a_, 0, 0, 0);
            a_ = __builtin_amdgcn_mfma_f32_16x16x32_bf16(a0h, B1l[g][0], a_, 0, 0, 0);
            a_ = __builtin_amdgcn_mfma_f32_16x16x32_bf16(a1h, B1l[g][1], a_, 0, 0, 0);
            a_ = __builtin_amdgcn_mfma_f32_16x16x32_bf16(a0l, B1h[g][0], a_, 0, 0, 0);
            a_ = __builtin_amdgcn_mfma_f32_16x16x32_bf16(a1l, B1h[g][1], a_, 0, 0, 0);
            zs[g] = a_;
          }
#pragma unroll
          for (int r = 0; r < 4; ++r) {
            float si = sigm_(zs[0][r]);
            float sf = sigm_(zs[1][r]);
            float tg = tanh_(zs[2][r]);
            float so = sigm_(zs[3][r]);
            float cc = sf * c1[mt * 4 + r] + si * tg;
            c1[mt * 4 + r] = cc;
            float h = so * tanh_(cc);
            unsigned short hh, hl;
            splitf_(h, hh, hl);
            const int m = mt * 16 + q * 4 + r;
            H1h[p][m * HSTR + j] = hh;
            H1l[p][m * HSTR + j] = hl;
          }
        }
        if (tt + 1 < T_) {  // stage x(tt+1) into the other XB buffer
          int m = (tid & 255) >> 2, ii = tid & 3;
          unsigned short xh, xl;
          splitf_(x[(mbase + m) * (T_ * I_) + (tt + 1) * I_ + ii], xh, xl);
          XB[(tt + 1) & 1][m * XSTR + ii] = xh;
          XB[(tt + 1) & 1][m * XSTR + 4 + ii] = xh;
          XB[(tt + 1) & 1][m * XSTR + 8 + ii] = xl;
        }
      }
      __syncthreads();  // barrier 1-per-iter, matched with L2 branch
    }
  } else {
    // ==================== LAYER-2 WAVES (4..7) ====================
    const int w2 = w - 4;
    const int j = w2 * 16 + l;
    short8 B2h[4][4], B2l[4][4];  // [0..1]=Wih1, [2..3]=Whh1
    floatx4 bias1v[4];
#pragma unroll
    for (int g = 0; g < 4; ++g) {
#pragma unroll
      for (int hf = 0; hf < 2; ++hf) {
        B2h[g][hf]     = wf[OFF_IH1H + (g * 2 + hf) * 256 + w2 * 64 + lane];
        B2l[g][hf]     = wf[OFF_IH1L + (g * 2 + hf) * 256 + w2 * 64 + lane];
        B2h[g][2 + hf] = wf[OFF_HH1H + (g * 2 + hf) * 256 + w2 * 64 + lane];
        B2l[g][2 + hf] = wf[OFF_HH1L + (g * 2 + hf) * 256 + w2 * 64 + lane];
      }
      float bb = b1[g * 64 + j];
      bias1v[g] = (floatx4){bb, bb, bb, bb};
    }
    float c2[16];
#pragma unroll
    for (int k = 0; k < 16; ++k) c2[k] = 0.f;

#pragma unroll 1
    for (int tt = 0; tt < T_ + 1; ++tt) {
      if (tt >= 1) {
        const int t2 = tt - 1;   // computing h2(t2)
        const int p2 = t2 & 1;   // read h1(t2) <- H1*[p2], h2(t2-1) <- H2*[p2^1]
        const bool do_out = (t2 % 5 == 4);
        const int kk = t2 / 5;
#pragma unroll
        for (int mt = 0; mt < 4; ++mt) {
          const int row = mt * 16 + l;
          short8 n0h = *(const short8*)&H1h[p2][row * HSTR + q * 8];
          short8 n1h = *(const short8*)&H1h[p2][row * HSTR + 32 + q * 8];
          short8 n0l = *(const short8*)&H1l[p2][row * HSTR + q * 8];
          short8 n1l = *(const short8*)&H1l[p2][row * HSTR + 32 + q * 8];
          short8 m0h = *(const short8*)&H2h[p2 ^ 1][row * HSTR + q * 8];
          short8 m1h = *(const short8*)&H2h[p2 ^ 1][row * HSTR + 32 + q * 8];
          short8 m0l = *(const short8*)&H2l[p2 ^ 1][row * HSTR + q * 8];
          short8 m1l = *(const short8*)&H2l[p2 ^ 1][row * HSTR + 32 + q * 8];
          floatx4 zs[4];
#pragma unroll
          for (int g = 0; g < 4; ++g) {
            floatx4 a_ = bias1v[g];
            a_ = __builtin_amdgcn_mfma_f32_16x16x32_bf16(n0h, B2h[g][0], a_, 0, 0, 0);
            a_ = __builtin_amdgcn_mfma_f32_16x16x32_bf16(n1h, B2h[g][1], a_, 0, 0, 0);
            a_ = __builtin_amdgcn_mfma_f32_16x16x32_bf16(n0h, B2l[g][0], a_, 0, 0, 0);
            a_ = __builtin_amdgcn_mfma_f32_16x16x32_bf16(n1h, B2l[g][1], a_, 0, 0, 0);
            a_ = __builtin_amdgcn_mfma_f32_16x16x32_bf16(n0l, B2h[g][0], a_, 0, 0, 0);
            a_ = __builtin_amdgcn_mfma_f32_16x16x32_bf16(n1l, B2h[g][1], a_, 0, 0, 0);
            a_ = __builtin_amdgcn_mfma_f32_16x16x32_bf16(m0h, B2h[g][2], a_, 0, 0, 0);
            a_ = __builtin_amdgcn_mfma_f32_16x16x32_bf16(m1h, B2h[g][3], a_, 0, 0, 0);
            a_ = __builtin_amdgcn_mfma_f32_16x16x32_bf16(m0h, B2l[g][2], a_, 0, 0, 0);
            a_ = __builtin_amdgcn_mfma_f32_16x16x32_bf16(m1h, B2l[g][3], a_, 0, 0, 0);
            a_ = __builtin_amdgcn_mfma_f32_16x16x32_bf16(m0l, B2h[g][2], a_, 0, 0, 0);
            a_ = __builtin_amdgcn_mfma_f32_16x16x32_bf16(m1l, B2h[g][3], a_, 0, 0, 0);
            zs[g] = a_;
          }
#pragma unroll
          for (int r = 0; r < 4; ++r) {
            float si = sigm_(zs[0][r]);
            float sf = sigm_(zs[1][r]);
            float tg = tanh_(zs[2][r]);
            float so = sigm_(zs[3][r]);
            float cc = sf * c2[mt * 4 + r] + si * tg;
            c2[mt * 4 + r] = cc;
            float h = so * tanh_(cc);
            unsigned short hh, hl;
            splitf_(h, hh, hl);
            const int m = mt * 16 + q * 4 + r;
            H2h[p2][m * HSTR + j] = hh;
            H2l[p2][m * HSTR + j] = hl;
            if (do_out) out[(size_t)(mbase + m) * 320 + (size_t)kk * 64 + j] = h;
          }
        }
      }
      __syncthreads();  // matched with L1 branch
    }
  }
}

extern "C" void kernel_launch(void* const* d_in, const int* in_sizes, int n_in,
                              void* d_out, int out_size, void* d_ws, size_t ws_size,
                              hipStream_t stream) {
  const float* xp   = (const float*)d_in[0];
  const float* Wih0 = (const float*)d_in[1];
  const float* Whh0 = (const float*)d_in[2];
  const float* b0   = (const float*)d_in[3];
  const float* Wih1 = (const float*)d_in[4];
  const float* Whh1 = (const float*)d_in[5];
  const float* b1   = (const float*)d_in[6];
  float* outp = (float*)d_out;
  unsigned short* ws = (unsigned short*)d_ws;

  // Pre-split weights into fragment-ordered hi/lo arrays (212992 B of d_ws).
  hipLaunchKernelGGL(prep_weights, dim3(28), dim3(256), 0, stream,
                     Wih0, Whh0, Wih1, Whh1, ws);

  const int B = in_sizes[0] / (T_ * I_);  // 65536
  dim3 grid(B / MB), block(512);
  hipLaunchKernelGGL(lstm2_kernel, grid, block, 0, stream,
                     xp, b0, b1, (const short8*)ws, outp);
}